// Round 1
// baseline (1003.096 us; speedup 1.0000x reference)
//
#include <hip/hip_runtime.h>
#include <math.h>

// Problem constants (from reference): inputs [32,64,64,64] f32, embedding [1024,64] f32
#define N_ROWS   131072      // 32*64*64
#define D        64
#define K_EMB    1024
#define M_TILE   64          // rows per block
#define KC       128         // embedding rows staged per chunk
#define XS_LD    68          // padded LDS stride (floats); 68*4B = 272B = 17*16B -> rows stay 16B aligned

// Output layout (floats): q_st[8388608] | q_orig[8388608] | perplexity[1] | encodings[134217728]
#define Q_ST_OFF   0
#define Q_OR_OFF   8388608
#define PERP_OFF   16777216
#define ENC_OFF    16777217   // NOTE: odd -> encodings region only 4B-aligned

// ws layout: [0,4096): uint counts[1024]; [4096,12288): double enorm[1024]

__global__ __launch_bounds__(256) void enorm_kernel(const float* __restrict__ emb,
                                                    double* __restrict__ enorm) {
    int k = blockIdx.x * 256 + threadIdx.x;
    if (k >= K_EMB) return;
    const float4* row = reinterpret_cast<const float4*>(emb + (size_t)k * D);
    double s = 0.0;
#pragma unroll
    for (int i = 0; i < D / 4; ++i) {
        float4 v = row[i];
        double a = (double)v.x, b = (double)v.y, c = (double)v.z, d = (double)v.w;
        s = fma(a, a, s); s = fma(b, b, s); s = fma(c, c, s); s = fma(d, d, s);
    }
    enorm[k] = s;
}

__global__ __launch_bounds__(256) void vq_main(const float* __restrict__ in,
                                               const float* __restrict__ emb,
                                               const double* __restrict__ enorm,
                                               unsigned int* __restrict__ counts,
                                               float* __restrict__ out) {
    __shared__ float Xs[M_TILE][XS_LD];
    __shared__ float Es[KC][XS_LD];
    __shared__ int   bks[M_TILE];

    const int tid = threadIdx.x;
    const int tr  = tid >> 4;    // 0..15 -> owns rows 4*tr..4*tr+3
    const int tc  = tid & 15;    // 0..15 -> owns k % 16 == tc lanes of each chunk
    const int base = blockIdx.x * M_TILE;

    // ---- stage X tile (64x64 f32, contiguous) ----
    {
        const float4* src = reinterpret_cast<const float4*>(in + (size_t)base * D);
#pragma unroll
        for (int i = 0; i < 4; ++i) {
            int lin = i * 256 + tid;            // 0..1023 float4s
            float4 v = src[lin];
            int row = lin >> 4;                 // 16 float4 per row
            int col = (lin & 15) << 2;
            *reinterpret_cast<float4*>(&Xs[row][col]) = v;
        }
    }

    double bestv[4];
    int    bestk[4];
#pragma unroll
    for (int r = 0; r < 4; ++r) { bestv[r] = 1e300; bestk[r] = 0; }

    for (int ch = 0; ch < K_EMB / KC; ++ch) {
        __syncthreads();   // protect Es re-use (also covers Xs staging on first iter)
        // ---- stage E chunk (128x64 f32, contiguous) ----
        {
            const float4* esrc = reinterpret_cast<const float4*>(emb + (size_t)ch * KC * D);
#pragma unroll
            for (int i = 0; i < 8; ++i) {
                int lin = i * 256 + tid;        // 0..2047 float4s
                float4 v = esrc[lin];
                int row = lin >> 4;
                int col = (lin & 15) << 2;
                *reinterpret_cast<float4*>(&Es[row][col]) = v;
            }
        }
        __syncthreads();

        // ---- fp64 dot products: 4 rows x 8 codes per thread ----
        double acc[4][8];
#pragma unroll
        for (int r = 0; r < 4; ++r)
#pragma unroll
            for (int c = 0; c < 8; ++c) acc[r][c] = 0.0;

#pragma unroll
        for (int db = 0; db < 16; ++db) {
            float xa[4][4];
            float eb[8][4];
#pragma unroll
            for (int r = 0; r < 4; ++r) {
                float4 t = *reinterpret_cast<const float4*>(&Xs[tr * 4 + r][db * 4]);
                xa[r][0] = t.x; xa[r][1] = t.y; xa[r][2] = t.z; xa[r][3] = t.w;
            }
#pragma unroll
            for (int c = 0; c < 8; ++c) {
                float4 t = *reinterpret_cast<const float4*>(&Es[tc + 16 * c][db * 4]);
                eb[c][0] = t.x; eb[c][1] = t.y; eb[c][2] = t.z; eb[c][3] = t.w;
            }
#pragma unroll
            for (int d = 0; d < 4; ++d) {
                double xd[4];
#pragma unroll
                for (int r = 0; r < 4; ++r) xd[r] = (double)xa[r][d];
#pragma unroll
                for (int c = 0; c < 8; ++c) {
                    double ed = (double)eb[c][d];
#pragma unroll
                    for (int r = 0; r < 4; ++r) acc[r][c] = fma(xd[r], ed, acc[r][c]);
                }
            }
        }

        // ---- update running argmin (k ascending within thread -> strict < = first index) ----
#pragma unroll
        for (int c = 0; c < 8; ++c) {
            int k = ch * KC + tc + 16 * c;
            double en = enorm[k];
#pragma unroll
            for (int r = 0; r < 4; ++r) {
                double s = fma(-2.0, acc[r][c], en);
                if (s < bestv[r]) { bestv[r] = s; bestk[r] = k; }
            }
        }
    }

    // ---- reduce across the 16 tc-lanes sharing each row (consecutive lanes in-wave) ----
#pragma unroll
    for (int r = 0; r < 4; ++r) {
        double v = bestv[r];
        int    kk = bestk[r];
#pragma unroll
        for (int off = 8; off >= 1; off >>= 1) {
            double ov = __shfl_xor(v, off, 64);
            int    ok = __shfl_xor(kk, off, 64);
            if (ov < v || (ov == v && ok < kk)) { v = ov; kk = ok; }
        }
        if (tc == 0) bks[tr * 4 + r] = kk;
    }

    // ---- zero-fill this block's encodings rows (64*1024 f32, region is 4B-aligned only) ----
    {
        float* ep = out + ENC_OFF + (size_t)base * K_EMB;   // float index ≡ 1 (mod 4) globally
        // aligned float4 span: [3, 65535), head scalars {0,1,2}, tail scalar {65535}
        float4 z4 = make_float4(0.f, 0.f, 0.f, 0.f);
        float4* ap = reinterpret_cast<float4*>(ep + 3);
        for (int i = tid; i < 16383; i += 256) ap[i] = z4;
        if (tid == 0) { ep[0] = 0.f; ep[1] = 0.f; ep[2] = 0.f; ep[65535] = 0.f; }
    }

    __syncthreads();   // bks visible + zeros complete

    // ---- one-hot + counts ----
    if (tid < M_TILE) {
        int kk = bks[tid];
        atomicAdd(&counts[kk], 1u);
        out[ENC_OFF + (size_t)(base + tid) * K_EMB + kk] = 1.0f;
    }

    // ---- quantized copy (both outputs identical): 4 threads per row ----
    {
        int row = tid >> 2;
        int p   = tid & 3;
        int kk  = bks[row];
        const float4* er = reinterpret_cast<const float4*>(emb + (size_t)kk * D);
        float4* o1 = reinterpret_cast<float4*>(out + Q_ST_OFF + (size_t)(base + row) * D);
        float4* o2 = reinterpret_cast<float4*>(out + Q_OR_OFF + (size_t)(base + row) * D);
#pragma unroll
        for (int i = 0; i < 4; ++i) {
            float4 v = er[p * 4 + i];
            o1[p * 4 + i] = v;
            o2[p * 4 + i] = v;
        }
    }
}

__global__ __launch_bounds__(1024) void perp_kernel(const unsigned int* __restrict__ counts,
                                                    float* __restrict__ out_perp) {
    const int k = threadIdx.x;
    double p = (double)counts[k] * (1.0 / (double)N_ROWS);
    double t = p * log(p + 1e-10);
    // full-wave reduce
#pragma unroll
    for (int off = 32; off >= 1; off >>= 1) t += __shfl_down(t, off, 64);
    __shared__ double red[16];
    if ((k & 63) == 0) red[k >> 6] = t;
    __syncthreads();
    if (k < 16) {
        double s = red[k];
#pragma unroll
        for (int off = 8; off >= 1; off >>= 1) s += __shfl_down(s, off, 16);
        if (k == 0) out_perp[0] = (float)exp(-s);
    }
}

extern "C" void kernel_launch(void* const* d_in, const int* in_sizes, int n_in,
                              void* d_out, int out_size, void* d_ws, size_t ws_size,
                              hipStream_t stream) {
    const float* in  = (const float*)d_in[0];
    const float* emb = (const float*)d_in[1];
    float* out = (float*)d_out;
    unsigned int* counts = (unsigned int*)d_ws;
    double* enorm = (double*)((char*)d_ws + 4096);

    hipMemsetAsync(d_ws, 0, 4096, stream);                       // zero counts
    enorm_kernel<<<K_EMB / 256, 256, 0, stream>>>(emb, enorm);
    vq_main<<<N_ROWS / M_TILE, 256, 0, stream>>>(in, emb, enorm, counts, out);
    perp_kernel<<<1, 1024, 0, stream>>>(counts, out + PERP_OFF);
}